// Round 2
// baseline (950.842 us; speedup 1.0000x reference)
//
#include <hip/hip_runtime.h>
#include <hip/hip_bf16.h>

#define B_ 16
#define S_ 80
#define D_ 512
#define H_ 64
#define DI_ 2048
#define L_ 6
#define G4H 256            // 4*H
#define NROW (B_ * S_)     // 1280 rows = (b, s)
#define EPS_ 1e-6f

typedef __attribute__((ext_vector_type(8))) short short8;
typedef __attribute__((ext_vector_type(4))) float f32x4;

// ---------------- math helpers ----------------
__device__ __forceinline__ float sigmoidf_(float x) {
    return __fdividef(1.0f, 1.0f + __expf(-x));
}
__device__ __forceinline__ float tanh_(float x) {
    return __fdividef(2.0f, 1.0f + __expf(-2.0f * x)) - 1.0f;
}
__device__ __forceinline__ short f2bf(float f) {
    __hip_bfloat16 h = __float2bfloat16(f);   // RNE
    return *reinterpret_cast<short*>(&h);
}

// Barrier that waits only on LDS traffic (lgkmcnt), NOT on in-flight global loads.
__device__ __forceinline__ void lds_barrier() {
    __asm__ volatile("s_waitcnt lgkmcnt(0)\n\ts_barrier" ::: "memory");
}

// ---------------- fp32 -> bf16 weight conversion (once per launch) ----------------
__global__ __launch_bounds__(256)
void w2bf_kernel(const float* __restrict__ s, __hip_bfloat16* __restrict__ d, int n4) {
    int i = blockIdx.x * 256 + threadIdx.x;
    if (i < n4) {
        float4 v = reinterpret_cast<const float4*>(s)[i];
        short4 o;
        o.x = f2bf(v.x); o.y = f2bf(v.y); o.z = f2bf(v.z); o.w = f2bf(v.w);
        reinterpret_cast<short4*>(d)[i] = o;
    }
}

// ---------------- LayerNorm: one block per row, shuffle reduce (2 barriers) ----------------
__global__ __launch_bounds__(256)
void ln_kernel(const float* __restrict__ x, const float* __restrict__ g,
               const float* __restrict__ b, __hip_bfloat16* __restrict__ out) {
    int row = blockIdx.x;
    int t = threadIdx.x;
    const float* xr = x + (size_t)row * D_;
    float v0 = xr[t], v1 = xr[t + 256];
    __shared__ float ws4[4], qs4[4];
    float s = v0 + v1;
    #pragma unroll
    for (int o = 32; o > 0; o >>= 1) s += __shfl_down(s, o);
    if ((t & 63) == 0) ws4[t >> 6] = s;
    __syncthreads();
    float m = (ws4[0] + ws4[1] + ws4[2] + ws4[3]) * (1.0f / (float)D_);
    float d0 = v0 - m, d1 = v1 - m;
    float q = d0 * d0 + d1 * d1;
    #pragma unroll
    for (int o = 32; o > 0; o >>= 1) q += __shfl_down(q, o);
    if ((t & 63) == 0) qs4[t >> 6] = q;
    __syncthreads();
    float rs = rsqrtf((qs4[0] + qs4[1] + qs4[2] + qs4[3]) * (1.0f / (float)D_) + EPS_);
    __hip_bfloat16* orow = out + (size_t)row * D_;
    orow[t]       = __float2bfloat16(d0 * rs * g[t]       + b[t]);
    orow[t + 256] = __float2bfloat16(d1 * rs * g[t + 256] + b[t + 256]);
}

// ---------------- bf16 MFMA GEMM: C[M,N] = A[M,K] @ W[N,K]^T (+bias)(+relu)(+res) -----------
// OUT_MODE: 0 = fp32 row-major, 1 = bf16 row-major,
//           2 = fp32 xg5 layout [s][half][gate][unit64][slot8]  (half=b>>3, slot=b&7)
template<int WITH_BIAS, int WITH_RELU, int WITH_RES, int OUT_MODE>
__global__ __launch_bounds__(256)
void mfma_gemm(const __hip_bfloat16* __restrict__ A, const __hip_bfloat16* __restrict__ W,
               const float* __restrict__ bias, const float* __restrict__ res,
               void* __restrict__ C, int M, int N, int K) {
    const int LDT = 72;  // LDS row stride in shorts (144B rows, 16B-aligned)
    __shared__ short As[64 * LDT];
    __shared__ short Ws[64 * LDT];

    int tid  = threadIdx.x;
    int wave = tid >> 6, lane = tid & 63;
    int quad = lane >> 4, l16 = lane & 15;
    int m_off = (wave >> 1) * 32, n_off = (wave & 1) * 32;
    int m0 = blockIdx.y * 64, n0 = blockIdx.x * 64;

    int r = tid >> 2, c = tid & 3;           // staging: row 0..63, 16-elem chunk 0..3
    const short* Ag = reinterpret_cast<const short*>(A);
    const short* Wg = reinterpret_cast<const short*>(W);

    f32x4 acc00 = {0.f,0.f,0.f,0.f}, acc01 = acc00, acc10 = acc00, acc11 = acc00;

    short8 avA[2], avW[2];                   // staged tile in registers
    auto load_tile = [&](int k0) {
        const short* arow = &Ag[(size_t)(m0 + r) * K + k0 + c * 16];
        avA[0] = *reinterpret_cast<const short8*>(arow);
        avA[1] = *reinterpret_cast<const short8*>(arow + 8);
        const short* wrow = &Wg[(size_t)(n0 + r) * K + k0 + c * 16];
        avW[0] = *reinterpret_cast<const short8*>(wrow);
        avW[1] = *reinterpret_cast<const short8*>(wrow + 8);
    };

    load_tile(0);                            // prologue
    for (int k0 = 0; k0 < K; k0 += 64) {
        lds_barrier();                       // prev frag reads done; vmem stays in flight
        *reinterpret_cast<short8*>(&As[r * LDT + c * 16])     = avA[0];
        *reinterpret_cast<short8*>(&As[r * LDT + c * 16 + 8]) = avA[1];
        *reinterpret_cast<short8*>(&Ws[r * LDT + c * 16])     = avW[0];
        *reinterpret_cast<short8*>(&Ws[r * LDT + c * 16 + 8]) = avW[1];
        lds_barrier();
        if (k0 + 64 < K) load_tile(k0 + 64); // issue next loads; consumed next iteration

        #pragma unroll
        for (int kc = 0; kc < 2; kc++) {
            short8 a0 = *reinterpret_cast<const short8*>(&As[(m_off + l16) * LDT + kc * 32 + quad * 8]);
            short8 a1 = *reinterpret_cast<const short8*>(&As[(m_off + 16 + l16) * LDT + kc * 32 + quad * 8]);
            short8 b0 = *reinterpret_cast<const short8*>(&Ws[(n_off + l16) * LDT + kc * 32 + quad * 8]);
            short8 b1 = *reinterpret_cast<const short8*>(&Ws[(n_off + 16 + l16) * LDT + kc * 32 + quad * 8]);
            acc00 = __builtin_amdgcn_mfma_f32_16x16x32_bf16(a0, b0, acc00, 0, 0, 0);
            acc01 = __builtin_amdgcn_mfma_f32_16x16x32_bf16(a0, b1, acc01, 0, 0, 0);
            acc10 = __builtin_amdgcn_mfma_f32_16x16x32_bf16(a1, b0, acc10, 0, 0, 0);
            acc11 = __builtin_amdgcn_mfma_f32_16x16x32_bf16(a1, b1, acc11, 0, 0, 0);
        }
    }

    f32x4 accs[2][2] = {{acc00, acc01}, {acc10, acc11}};
    #pragma unroll
    for (int fi = 0; fi < 2; fi++) {
        #pragma unroll
        for (int fj = 0; fj < 2; fj++) {
            int coln = n0 + n_off + fj * 16 + l16;
            float bv = WITH_BIAS ? bias[coln] : 0.0f;
            #pragma unroll
            for (int rr = 0; rr < 4; rr++) {
                int rowm = m0 + m_off + fi * 16 + quad * 4 + rr;
                float v = accs[fi][fj][rr];
                if (WITH_BIAS) v += bv;
                if (WITH_RELU) v = fmaxf(v, 0.0f);
                if (WITH_RES)  v += res[(size_t)rowm * N + coln];
                if (OUT_MODE == 0) {
                    reinterpret_cast<float*>(C)[(size_t)rowm * N + coln] = v;
                } else if (OUT_MODE == 1) {
                    reinterpret_cast<__hip_bfloat16*>(C)[(size_t)rowm * N + coln] = __float2bfloat16(v);
                } else {
                    int b_ = rowm / S_;
                    int s_ = rowm - b_ * S_;
                    int gate = coln >> 6, u = coln & 63;
                    int half = b_ >> 3, slot = b_ & 7;
                    reinterpret_cast<float*>(C)[
                        ((((size_t)(s_ * 2 + half) * 4 + gate) * 64 + u) << 3) + slot] = v;
                }
            }
        }
    }
}

// ---------------- MFMA LSTM v6: v4 structure + dual independent streams per wave ----------
// v4 (measured 1650 cy/step) spent ~1070 cy/step in exposed LDS/barrier/MFMA latency at
// 0.6 waves/SIMD (nothing to overlap with). v6 gives every wave TWO independent
// recurrence streams: batch-half 0 and batch-half 1 of the SAME output position i.
// They share the in-register Whh fragments and the same xg row; their MFMA/VALU issue
// mutually fills the other stream's LDS round-trip and MFMA latency, under ONE shared
// per-step lds_barrier. Grid: 80 blocks (one per position), 4 waves (16 units each).
// Per lane per step: 2x2 = 4 states.
__global__ __launch_bounds__(256)
void lstm_v6_kernel(const float* __restrict__ xg5,  // [S][2][4][64][8] fp32
                    const float* __restrict__ whh,  // [4H, H] fp32 (layer slice)
                    __hip_bfloat16* __restrict__ hlast) {  // [B, S, H]
    const int i    = blockIdx.x;      // output position 0..79
    const int tid  = threadIdx.x;
    const int wave = tid >> 6, lane = tid & 63;
    const int quad = lane >> 4, l16 = lane & 15;
    const int unit = wave * 16 + l16; // hidden unit owned on the C side

    // Whh B-fragments (bf16), one-time. Tile g: col n = l16 <-> whh row g*64 + unit.
    short8 bfrag[4][2];
    #pragma unroll
    for (int g = 0; g < 4; g++) {
        const float* wr = &whh[(size_t)(g * 64 + unit) * H_];
        #pragma unroll
        for (int kc = 0; kc < 2; kc++) {
            float4 x0 = *(const float4*)(wr + kc * 32 + quad * 8);
            float4 x1 = *(const float4*)(wr + kc * 32 + quad * 8 + 4);
            short8 v;
            v[0] = f2bf(x0.x); v[1] = f2bf(x0.y); v[2] = f2bf(x0.z); v[3] = f2bf(x0.w);
            v[4] = f2bf(x1.x); v[5] = f2bf(x1.y); v[6] = f2bf(x1.z); v[7] = f2bf(x1.w);
            bfrag[g][kc] = v;
        }
    }

    // h in LDS: [stream][parity][row][col], 72-short rows (144B, 16B-aligned).
    // Rows {0,1,4,5,8,9,12,13} hold batches; rows 2,3,6,7,... stay zero forever.
    __shared__ __attribute__((aligned(16))) short hsh[2][2][16][72];
    for (int idx = tid; idx < 2 * 2 * 16 * 72; idx += 256)
        reinterpret_cast<short*>(hsh)[idx] = 0;

    float cstA[2] = {0.f, 0.f}, cstB[2] = {0.f, 0.f};
    float hvA[2]  = {0.f, 0.f}, hvB[2]  = {0.f, 0.f};

    // xg float2 addresses: (((s*2+bh)*4 + g)*64 + unit)*8 + quad*2
    size_t xoffA[4], xoffB[4];
    #pragma unroll
    for (int g = 0; g < 4; g++) {
        xoffA[g] = (((size_t)(0 * 4 + g) * 64 + unit) << 3) + quad * 2;
        xoffB[g] = (((size_t)(1 * 4 + g) * 64 + unit) << 3) + quad * 2;
    }

    float2 xvA[4], xvB[4];
    auto xload = [&](int t) {
        int s = (t == i) ? (S_ - 1) : ((t == S_ - 1) ? i : t);   // janossy permutation
        const float* base = xg5 + (size_t)s * 4096;
        #pragma unroll
        for (int g = 0; g < 4; g++) {
            xvA[g] = *reinterpret_cast<const float2*>(base + xoffA[g]);
            xvB[g] = *reinterpret_cast<const float2*>(base + xoffB[g]);
        }
    };
    xload(0);

    lds_barrier();  // LDS zero-init visible

    for (int t = 0; t < S_; t++) {
        const int pb = t & 1;
        // issue both streams' A-frag reads first (independent latency)
        short8 a0A = *reinterpret_cast<const short8*>(&hsh[0][pb][l16][quad * 8]);
        short8 a1A = *reinterpret_cast<const short8*>(&hsh[0][pb][l16][32 + quad * 8]);
        short8 a0B = *reinterpret_cast<const short8*>(&hsh[1][pb][l16][quad * 8]);
        short8 a1B = *reinterpret_cast<const short8*>(&hsh[1][pb][l16][32 + quad * 8]);

        f32x4 accA[4], accB[4];
        #pragma unroll
        for (int g = 0; g < 4; g++) {
            accA[g] = f32x4{xvA[g].x, xvA[g].y, 0.f, 0.f};
            accB[g] = f32x4{xvB[g].x, xvB[g].y, 0.f, 0.f};
        }

        // prefetch next step's xg (both streams; stays in flight across the barrier)
        if (t + 1 < S_) xload(t + 1);

        #pragma unroll
        for (int g = 0; g < 4; g++) {
            accA[g] = __builtin_amdgcn_mfma_f32_16x16x32_bf16(a0A, bfrag[g][0], accA[g], 0, 0, 0);
            accA[g] = __builtin_amdgcn_mfma_f32_16x16x32_bf16(a1A, bfrag[g][1], accA[g], 0, 0, 0);
            accB[g] = __builtin_amdgcn_mfma_f32_16x16x32_bf16(a0B, bfrag[g][0], accB[g], 0, 0, 0);
            accB[g] = __builtin_amdgcn_mfma_f32_16x16x32_bf16(a1B, bfrag[g][1], accB[g], 0, 0, 0);
        }

        #pragma unroll
        for (int r = 0; r < 2; r++) {
            {   // stream A (batches 0..7)
                float ig = sigmoidf_(accA[0][r]);
                float fg = sigmoidf_(accA[1][r]);
                float gg = tanh_(accA[2][r]);
                float og = sigmoidf_(accA[3][r]);
                float cc = fg * cstA[r] + ig * gg;
                cstA[r] = cc;
                float h = og * tanh_(cc);
                hvA[r] = h;
                hsh[0][pb ^ 1][quad * 4 + r][unit] = f2bf(h);
            }
            {   // stream B (batches 8..15)
                float ig = sigmoidf_(accB[0][r]);
                float fg = sigmoidf_(accB[1][r]);
                float gg = tanh_(accB[2][r]);
                float og = sigmoidf_(accB[3][r]);
                float cc = fg * cstB[r] + ig * gg;
                cstB[r] = cc;
                float h = og * tanh_(cc);
                hvB[r] = h;
                hsh[1][pb ^ 1][quad * 4 + r][unit] = f2bf(h);
            }
        }
        lds_barrier();
    }

    #pragma unroll
    for (int r = 0; r < 2; r++) {
        int bA = quad * 2 + r;          // batches 0..7
        int bB = 8 + quad * 2 + r;      // batches 8..15
        hlast[((size_t)bA * S_ + i) * H_ + unit] = __float2bfloat16(hvA[r]);
        hlast[((size_t)bB * S_ + i) * H_ + unit] = __float2bfloat16(hvB[r]);
    }
}

// ---------------- final LN + projection to one logit per row ----------------
__global__ __launch_bounds__(256)
void final_kernel(const float* __restrict__ x, const float* __restrict__ g,
                  const float* __restrict__ b, const float* __restrict__ wprj,
                  float* __restrict__ out) {
    int row = blockIdx.x;
    int t = threadIdx.x;
    const float* xr = x + (size_t)row * D_;
    float v0 = xr[t], v1 = xr[t + 256];
    __shared__ float red[256];
    red[t] = v0 + v1;
    __syncthreads();
    for (int o = 128; o > 0; o >>= 1) { if (t < o) red[t] += red[t + o]; __syncthreads(); }
    float m = red[0] * (1.0f / (float)D_);
    __syncthreads();
    float d0 = v0 - m, d1 = v1 - m;
    red[t] = d0 * d0 + d1 * d1;
    __syncthreads();
    for (int o = 128; o > 0; o >>= 1) { if (t < o) red[t] += red[t + o]; __syncthreads(); }
    float rs = rsqrtf(red[0] * (1.0f / (float)D_) + EPS_);
    __syncthreads();
    float y0 = (d0 * rs * g[t] + b[t]) * wprj[t];
    float y1 = (d1 * rs * g[t + 256] + b[t + 256]) * wprj[t + 256];
    red[t] = y0 + y1;
    __syncthreads();
    for (int o = 128; o > 0; o >>= 1) { if (t < o) red[t] += red[t + o]; __syncthreads(); }
    if (t == 0) out[row] = red[0];
}

// ---------------- host ----------------
extern "C" void kernel_launch(void* const* d_in, const int* in_sizes, int n_in,
                              void* d_out, int out_size, void* d_ws, size_t ws_size,
                              hipStream_t stream) {
    const float* src   = (const float*)d_in[0];
    const float* ln1_g = (const float*)d_in[2];
    const float* ln1_b = (const float*)d_in[3];
    const float* wih   = (const float*)d_in[4];   // [L, 4H, D]
    const float* whh   = (const float*)d_in[5];   // [L, 4H, H]
    const float* wfc   = (const float*)d_in[6];   // [L, D, H]
    const float* ln2_g = (const float*)d_in[7];
    const float* ln2_b = (const float*)d_in[8];
    const float* w1    = (const float*)d_in[9];   // [L, DI, D]
    const float* b1    = (const float*)d_in[10];  // [L, DI]
    const float* w2    = (const float*)d_in[11];  // [L, D, DI]
    const float* b2    = (const float*)d_in[12];  // [L, D]
    const float* lnf_g = (const float*)d_in[13];
    const float* lnf_b = (const float*)d_in[14];
    const float* wprj  = (const float*)d_in[15];  // [1, D]
    float* out = (float*)d_out;

    char* ws = (char*)d_ws;
    float* xcur = (float*)ws;                       ws += (size_t)NROW * D_  * 4;  // fp32 residual stream
    __hip_bfloat16* lnb = (__hip_bfloat16*)ws;      ws += (size_t)NROW * D_  * 2;  // LN output (bf16 A-operand)
    float* xg5  = (float*)ws;                       ws += (size_t)S_ * 4096  * 4;  // gate proj fp32 [s][2][4][64][8]
    __hip_bfloat16* hb  = (__hip_bfloat16*)ws;      ws += (size_t)NROW * H_  * 2;  // LSTM h (bf16 A-operand)
    __hip_bfloat16* f1  = (__hip_bfloat16*)ws;      ws += (size_t)NROW * DI_ * 2;  // FFN hidden (bf16 A-operand)
    __hip_bfloat16* wihb = (__hip_bfloat16*)ws;     ws += (size_t)L_ * G4H * D_ * 2;
    __hip_bfloat16* wfcb = (__hip_bfloat16*)ws;     ws += (size_t)L_ * D_ * H_ * 2;
    __hip_bfloat16* w1b  = (__hip_bfloat16*)ws;     ws += (size_t)L_ * DI_ * D_ * 2;
    __hip_bfloat16* w2b  = (__hip_bfloat16*)ws;     ws += (size_t)L_ * D_ * DI_ * 2;

    // one-time (per launch) weight conversions to bf16
    {
        int n4;
        n4 = L_ * G4H * D_ / 4;
        w2bf_kernel<<<(n4 + 255) / 256, 256, 0, stream>>>(wih, wihb, n4);
        n4 = L_ * D_ * H_ / 4;
        w2bf_kernel<<<(n4 + 255) / 256, 256, 0, stream>>>(wfc, wfcb, n4);
        n4 = L_ * DI_ * D_ / 4;
        w2bf_kernel<<<(n4 + 255) / 256, 256, 0, stream>>>(w1, w1b, n4);
        n4 = L_ * D_ * DI_ / 4;
        w2bf_kernel<<<(n4 + 255) / 256, 256, 0, stream>>>(w2, w2b, n4);
    }

    hipMemcpyAsync(xcur, src, (size_t)NROW * D_ * sizeof(float),
                   hipMemcpyDeviceToDevice, stream);

    for (int l = 0; l < L_; l++) {
        // --- janossy layer ---
        ln_kernel<<<NROW, 256, 0, stream>>>(xcur, ln1_g + (size_t)l * D_,
                                            ln1_b + (size_t)l * D_, lnb);
        mfma_gemm<0, 0, 0, 2><<<dim3(G4H / 64, NROW / 64), 256, 0, stream>>>(
            lnb, wihb + (size_t)l * G4H * D_, nullptr, nullptr, xg5, NROW, G4H, D_);
        lstm_v6_kernel<<<dim3(S_), 256, 0, stream>>>(
            xg5, whh + (size_t)l * G4H * H_, hb);
        mfma_gemm<0, 0, 1, 0><<<dim3(D_ / 64, NROW / 64), 256, 0, stream>>>(
            hb, wfcb + (size_t)l * D_ * H_, nullptr, xcur, xcur, NROW, D_, H_);
        // --- FFN ---
        ln_kernel<<<NROW, 256, 0, stream>>>(xcur, ln2_g + (size_t)l * D_,
                                            ln2_b + (size_t)l * D_, lnb);
        mfma_gemm<1, 1, 0, 1><<<dim3(DI_ / 64, NROW / 64), 256, 0, stream>>>(
            lnb, w1b + (size_t)l * DI_ * D_, b1 + (size_t)l * DI_, nullptr, f1, NROW, DI_, D_);
        mfma_gemm<1, 0, 1, 0><<<dim3(D_ / 64, NROW / 64), 256, 0, stream>>>(
            f1, w2b + (size_t)l * D_ * DI_, b2 + (size_t)l * D_, xcur, xcur, NROW, D_, DI_);
    }
    final_kernel<<<NROW, 256, 0, stream>>>(xcur, lnf_g, lnf_b, wprj, out);
}

// Round 3
// 826.666 us; speedup vs baseline: 1.1502x; 1.1502x over previous
//
#include <hip/hip_runtime.h>
#include <hip/hip_bf16.h>

#define B_ 16
#define S_ 80
#define D_ 512
#define H_ 64
#define DI_ 2048
#define L_ 6
#define G4H 256            // 4*H
#define NROW (B_ * S_)     // 1280 rows = (b, s)
#define EPS_ 1e-6f

typedef __attribute__((ext_vector_type(8))) short short8;
typedef __attribute__((ext_vector_type(4))) float f32x4;

// ---------------- math helpers ----------------
__device__ __forceinline__ float sigmoidf_(float x) {
    return __fdividef(1.0f, 1.0f + __expf(-x));
}
__device__ __forceinline__ float tanh_(float x) {
    return __fdividef(2.0f, 1.0f + __expf(-2.0f * x)) - 1.0f;
}
__device__ __forceinline__ short f2bf(float f) {
    __hip_bfloat16 h = __float2bfloat16(f);   // RNE
    return *reinterpret_cast<short*>(&h);
}

// Barrier that waits only on LDS traffic (lgkmcnt), NOT on in-flight global loads.
__device__ __forceinline__ void lds_barrier() {
    __asm__ volatile("s_waitcnt lgkmcnt(0)\n\ts_barrier" ::: "memory");
}

// async global->LDS, 16B per lane. LDS dest = wave-uniform base + lane*16 (HW rule).
__device__ __forceinline__ void gll16(const float* g, float* l) {
    __builtin_amdgcn_global_load_lds(
        (const __attribute__((address_space(1))) unsigned int*)g,
        (__attribute__((address_space(3))) unsigned int*)l, 16, 0, 0);
}

// ---------------- fp32 -> bf16 weight conversion (once per launch) ----------------
__global__ __launch_bounds__(256)
void w2bf_kernel(const float* __restrict__ s, __hip_bfloat16* __restrict__ d, int n4) {
    int i = blockIdx.x * 256 + threadIdx.x;
    if (i < n4) {
        float4 v = reinterpret_cast<const float4*>(s)[i];
        short4 o;
        o.x = f2bf(v.x); o.y = f2bf(v.y); o.z = f2bf(v.z); o.w = f2bf(v.w);
        reinterpret_cast<short4*>(d)[i] = o;
    }
}

// ---------------- LayerNorm: one block per row, shuffle reduce (2 barriers) ----------------
__global__ __launch_bounds__(256)
void ln_kernel(const float* __restrict__ x, const float* __restrict__ g,
               const float* __restrict__ b, __hip_bfloat16* __restrict__ out) {
    int row = blockIdx.x;
    int t = threadIdx.x;
    const float* xr = x + (size_t)row * D_;
    float v0 = xr[t], v1 = xr[t + 256];
    __shared__ float ws4[4], qs4[4];
    float s = v0 + v1;
    #pragma unroll
    for (int o = 32; o > 0; o >>= 1) s += __shfl_down(s, o);
    if ((t & 63) == 0) ws4[t >> 6] = s;
    __syncthreads();
    float m = (ws4[0] + ws4[1] + ws4[2] + ws4[3]) * (1.0f / (float)D_);
    float d0 = v0 - m, d1 = v1 - m;
    float q = d0 * d0 + d1 * d1;
    #pragma unroll
    for (int o = 32; o > 0; o >>= 1) q += __shfl_down(q, o);
    if ((t & 63) == 0) qs4[t >> 6] = q;
    __syncthreads();
    float rs = rsqrtf((qs4[0] + qs4[1] + qs4[2] + qs4[3]) * (1.0f / (float)D_) + EPS_);
    __hip_bfloat16* orow = out + (size_t)row * D_;
    orow[t]       = __float2bfloat16(d0 * rs * g[t]       + b[t]);
    orow[t + 256] = __float2bfloat16(d1 * rs * g[t + 256] + b[t + 256]);
}

// ---------------- bf16 MFMA GEMM: C[M,N] = A[M,K] @ W[N,K]^T (+bias)(+relu)(+res) -----------
// OUT_MODE: 0 = fp32 row-major, 1 = bf16 row-major,
//           2 = fp32 xg5 layout [s][half][gate][unit64][slot8]  (half=b>>3, slot=b&7)
template<int WITH_BIAS, int WITH_RELU, int WITH_RES, int OUT_MODE>
__global__ __launch_bounds__(256)
void mfma_gemm(const __hip_bfloat16* __restrict__ A, const __hip_bfloat16* __restrict__ W,
               const float* __restrict__ bias, const float* __restrict__ res,
               void* __restrict__ C, int M, int N, int K) {
    const int LDT = 72;  // LDS row stride in shorts (144B rows, 16B-aligned)
    __shared__ short As[64 * LDT];
    __shared__ short Ws[64 * LDT];

    int tid  = threadIdx.x;
    int wave = tid >> 6, lane = tid & 63;
    int quad = lane >> 4, l16 = lane & 15;
    int m_off = (wave >> 1) * 32, n_off = (wave & 1) * 32;
    int m0 = blockIdx.y * 64, n0 = blockIdx.x * 64;

    int r = tid >> 2, c = tid & 3;           // staging: row 0..63, 16-elem chunk 0..3
    const short* Ag = reinterpret_cast<const short*>(A);
    const short* Wg = reinterpret_cast<const short*>(W);

    f32x4 acc00 = {0.f,0.f,0.f,0.f}, acc01 = acc00, acc10 = acc00, acc11 = acc00;

    short8 avA[2], avW[2];                   // staged tile in registers
    auto load_tile = [&](int k0) {
        const short* arow = &Ag[(size_t)(m0 + r) * K + k0 + c * 16];
        avA[0] = *reinterpret_cast<const short8*>(arow);
        avA[1] = *reinterpret_cast<const short8*>(arow + 8);
        const short* wrow = &Wg[(size_t)(n0 + r) * K + k0 + c * 16];
        avW[0] = *reinterpret_cast<const short8*>(wrow);
        avW[1] = *reinterpret_cast<const short8*>(wrow + 8);
    };

    load_tile(0);                            // prologue
    for (int k0 = 0; k0 < K; k0 += 64) {
        lds_barrier();                       // prev frag reads done; vmem stays in flight
        *reinterpret_cast<short8*>(&As[r * LDT + c * 16])     = avA[0];
        *reinterpret_cast<short8*>(&As[r * LDT + c * 16 + 8]) = avA[1];
        *reinterpret_cast<short8*>(&Ws[r * LDT + c * 16])     = avW[0];
        *reinterpret_cast<short8*>(&Ws[r * LDT + c * 16 + 8]) = avW[1];
        lds_barrier();
        if (k0 + 64 < K) load_tile(k0 + 64); // issue next loads; consumed next iteration

        #pragma unroll
        for (int kc = 0; kc < 2; kc++) {
            short8 a0 = *reinterpret_cast<const short8*>(&As[(m_off + l16) * LDT + kc * 32 + quad * 8]);
            short8 a1 = *reinterpret_cast<const short8*>(&As[(m_off + 16 + l16) * LDT + kc * 32 + quad * 8]);
            short8 b0 = *reinterpret_cast<const short8*>(&Ws[(n_off + l16) * LDT + kc * 32 + quad * 8]);
            short8 b1 = *reinterpret_cast<const short8*>(&Ws[(n_off + 16 + l16) * LDT + kc * 32 + quad * 8]);
            acc00 = __builtin_amdgcn_mfma_f32_16x16x32_bf16(a0, b0, acc00, 0, 0, 0);
            acc01 = __builtin_amdgcn_mfma_f32_16x16x32_bf16(a0, b1, acc01, 0, 0, 0);
            acc10 = __builtin_amdgcn_mfma_f32_16x16x32_bf16(a1, b0, acc10, 0, 0, 0);
            acc11 = __builtin_amdgcn_mfma_f32_16x16x32_bf16(a1, b1, acc11, 0, 0, 0);
        }
    }

    f32x4 accs[2][2] = {{acc00, acc01}, {acc10, acc11}};
    #pragma unroll
    for (int fi = 0; fi < 2; fi++) {
        #pragma unroll
        for (int fj = 0; fj < 2; fj++) {
            int coln = n0 + n_off + fj * 16 + l16;
            float bv = WITH_BIAS ? bias[coln] : 0.0f;
            #pragma unroll
            for (int rr = 0; rr < 4; rr++) {
                int rowm = m0 + m_off + fi * 16 + quad * 4 + rr;
                float v = accs[fi][fj][rr];
                if (WITH_BIAS) v += bv;
                if (WITH_RELU) v = fmaxf(v, 0.0f);
                if (WITH_RES)  v += res[(size_t)rowm * N + coln];
                if (OUT_MODE == 0) {
                    reinterpret_cast<float*>(C)[(size_t)rowm * N + coln] = v;
                } else if (OUT_MODE == 1) {
                    reinterpret_cast<__hip_bfloat16*>(C)[(size_t)rowm * N + coln] = __float2bfloat16(v);
                } else {
                    int b_ = rowm / S_;
                    int s_ = rowm - b_ * S_;
                    int gate = coln >> 6, u = coln & 63;
                    int half = b_ >> 3, slot = b_ & 7;
                    reinterpret_cast<float*>(C)[
                        ((((size_t)(s_ * 2 + half) * 4 + gate) * 64 + u) << 3) + slot] = v;
                }
            }
        }
    }
}

// ---------------- MFMA LSTM v7: v4 structure + LDS ring staging for xg ----------------
// v4's ~1650 cy/step was ~600 cy issue + ~1000 cy exposed GLOBAL latency on the
// per-step xg loads (1-step register prefetch window too short; 20% of xg demand
// misses to HBM at ~900 cy). v7 stages each step's 8KB contiguous xg chunk into a
// 4-slot LDS ring with global_load_lds, issued 3 steps ahead, with COUNTED
// s_waitcnt vmcnt(4) (never 0) so loads stay in flight across the per-step barrier.
// Per-step xg access is then 4x ds_read_b64 (~120cy, hidden under MFMA/VALU issue).
// Grid (80,2): block = (position i, batch half), 4 waves, 2 states/lane (v4 mapping).
__global__ __launch_bounds__(256, 1)
void lstm_v7_kernel(const float* __restrict__ xg5,  // [S][2][4][64][8] fp32
                    const float* __restrict__ whh,  // [4H, H] fp32 (layer slice)
                    __hip_bfloat16* __restrict__ hlast) {  // [B, S, H]
    const int i    = blockIdx.x;      // output position 0..79
    const int bh   = blockIdx.y;      // batch half 0..1
    const int tid  = threadIdx.x;
    const int wave = tid >> 6, lane = tid & 63;
    const int quad = lane >> 4, l16 = lane & 15;
    const int unit = wave * 16 + l16; // hidden unit owned on the C side

    // Whh B-fragments (bf16), one-time. Tile g: col n = l16 <-> whh row g*64 + unit.
    short8 bfrag[4][2];
    #pragma unroll
    for (int g = 0; g < 4; g++) {
        const float* wr = &whh[(size_t)(g * 64 + unit) * H_];
        #pragma unroll
        for (int kc = 0; kc < 2; kc++) {
            float4 x0 = *(const float4*)(wr + kc * 32 + quad * 8);
            float4 x1 = *(const float4*)(wr + kc * 32 + quad * 8 + 4);
            short8 v;
            v[0] = f2bf(x0.x); v[1] = f2bf(x0.y); v[2] = f2bf(x0.z); v[3] = f2bf(x0.w);
            v[4] = f2bf(x1.x); v[5] = f2bf(x1.y); v[6] = f2bf(x1.z); v[7] = f2bf(x1.w);
            bfrag[g][kc] = v;
        }
    }

    // h in LDS, double-buffered by step parity; 72-short rows (144B, 16B-aligned)
    __shared__ __attribute__((aligned(16))) short hsh[2][16][72];
    // 4-slot xg ring: one 8KB chunk = [gate 4][unit 64][slot 8] fp32 per step
    __shared__ __attribute__((aligned(16))) float xring[4][2048];

    for (int idx = tid; idx < 2 * 16 * 72; idx += 256)
        reinterpret_cast<short*>(hsh)[idx] = 0;

    // stage step-t chunk into ring slot t&3: wave w covers floats [(j*4+w)*256, +256)
    // per issue j=0,1; 64 lanes x 16B per issue. LDS dest linear (HW adds lane*16).
    auto stage = [&](int t) {
        int s = (t == i) ? (S_ - 1) : ((t == S_ - 1) ? i : t);   // janossy permutation
        const float* gsrc = xg5 + ((size_t)s * 2 + bh) * 2048;
        float* lbase = &xring[t & 3][0];
        #pragma unroll
        for (int j = 0; j < 2; j++) {
            int off = (j * 4 + wave) * 256;
            gll16(gsrc + off + lane * 4, lbase + off);
        }
    };

    float cst[2] = {0.f, 0.f};
    float hvv[2] = {0.f, 0.f};

    stage(0); stage(1); stage(2);            // prologue: 6 loads in flight per wave
    __asm__ volatile("s_waitcnt vmcnt(4)" ::: "memory");   // slot 0 landed (this wave)
    lds_barrier();                           // all waves' slot-0 + h zero-init visible

    for (int t = 0; t < S_; t++) {
        const int pb = t & 1;
        if (t + 3 < S_) stage(t + 3);        // overwrites slot (t-1)&3: readers done at t-1 barrier

        short8 af0 = *reinterpret_cast<const short8*>(&hsh[pb][l16][quad * 8]);
        short8 af1 = *reinterpret_cast<const short8*>(&hsh[pb][l16][32 + quad * 8]);

        const float* xb = &xring[t & 3][(unit << 3) + quad * 2];
        float2 xv0 = *reinterpret_cast<const float2*>(xb);            // gate i
        float2 xv1 = *reinterpret_cast<const float2*>(xb + 512);      // gate f
        float2 xv2 = *reinterpret_cast<const float2*>(xb + 1024);     // gate g
        float2 xv3 = *reinterpret_cast<const float2*>(xb + 1536);     // gate o

        f32x4 acc[4];
        acc[0] = f32x4{xv0.x, xv0.y, 0.f, 0.f};
        acc[1] = f32x4{xv1.x, xv1.y, 0.f, 0.f};
        acc[2] = f32x4{xv2.x, xv2.y, 0.f, 0.f};
        acc[3] = f32x4{xv3.x, xv3.y, 0.f, 0.f};

        #pragma unroll
        for (int g = 0; g < 4; g++) {
            acc[g] = __builtin_amdgcn_mfma_f32_16x16x32_bf16(af0, bfrag[g][0], acc[g], 0, 0, 0);
            acc[g] = __builtin_amdgcn_mfma_f32_16x16x32_bf16(af1, bfrag[g][1], acc[g], 0, 0, 0);
        }

        #pragma unroll
        for (int r = 0; r < 2; r++) {
            float ig = sigmoidf_(acc[0][r]);
            float fg = sigmoidf_(acc[1][r]);
            float gg = tanh_(acc[2][r]);
            float og = sigmoidf_(acc[3][r]);
            float cc = fg * cst[r] + ig * gg;
            cst[r] = cc;
            float h = og * tanh_(cc);
            hvv[r] = h;
            hsh[pb ^ 1][quad * 4 + r][unit] = f2bf(h);
        }

        // counted vmcnt: slot t+1's 2 loads (oldest) done; slots t+2,t+3 stay in flight
        if (t < 77)       { __asm__ volatile("s_waitcnt vmcnt(4)" ::: "memory"); }
        else if (t == 77) { __asm__ volatile("s_waitcnt vmcnt(2)" ::: "memory"); }
        else if (t == 78) { __asm__ volatile("s_waitcnt vmcnt(0)" ::: "memory"); }
        lds_barrier();
    }

    #pragma unroll
    for (int r = 0; r < 2; r++) {
        int b = bh * 8 + quad * 2 + r;
        hlast[((size_t)b * S_ + i) * H_ + unit] = __float2bfloat16(hvv[r]);
    }
}

// ---------------- final LN + projection to one logit per row ----------------
__global__ __launch_bounds__(256)
void final_kernel(const float* __restrict__ x, const float* __restrict__ g,
                  const float* __restrict__ b, const float* __restrict__ wprj,
                  float* __restrict__ out) {
    int row = blockIdx.x;
    int t = threadIdx.x;
    const float* xr = x + (size_t)row * D_;
    float v0 = xr[t], v1 = xr[t + 256];
    __shared__ float red[256];
    red[t] = v0 + v1;
    __syncthreads();
    for (int o = 128; o > 0; o >>= 1) { if (t < o) red[t] += red[t + o]; __syncthreads(); }
    float m = red[0] * (1.0f / (float)D_);
    __syncthreads();
    float d0 = v0 - m, d1 = v1 - m;
    red[t] = d0 * d0 + d1 * d1;
    __syncthreads();
    for (int o = 128; o > 0; o >>= 1) { if (t < o) red[t] += red[t + o]; __syncthreads(); }
    float rs = rsqrtf(red[0] * (1.0f / (float)D_) + EPS_);
    __syncthreads();
    float y0 = (d0 * rs * g[t] + b[t]) * wprj[t];
    float y1 = (d1 * rs * g[t + 256] + b[t + 256]) * wprj[t + 256];
    red[t] = y0 + y1;
    __syncthreads();
    for (int o = 128; o > 0; o >>= 1) { if (t < o) red[t] += red[t + o]; __syncthreads(); }
    if (t == 0) out[row] = red[0];
}

// ---------------- host ----------------
extern "C" void kernel_launch(void* const* d_in, const int* in_sizes, int n_in,
                              void* d_out, int out_size, void* d_ws, size_t ws_size,
                              hipStream_t stream) {
    const float* src   = (const float*)d_in[0];
    const float* ln1_g = (const float*)d_in[2];
    const float* ln1_b = (const float*)d_in[3];
    const float* wih   = (const float*)d_in[4];   // [L, 4H, D]
    const float* whh   = (const float*)d_in[5];   // [L, 4H, H]
    const float* wfc   = (const float*)d_in[6];   // [L, D, H]
    const float* ln2_g = (const float*)d_in[7];
    const float* ln2_b = (const float*)d_in[8];
    const float* w1    = (const float*)d_in[9];   // [L, DI, D]
    const float* b1    = (const float*)d_in[10];  // [L, DI]
    const float* w2    = (const float*)d_in[11];  // [L, D, DI]
    const float* b2    = (const float*)d_in[12];  // [L, D]
    const float* lnf_g = (const float*)d_in[13];
    const float* lnf_b = (const float*)d_in[14];
    const float* wprj  = (const float*)d_in[15];  // [1, D]
    float* out = (float*)d_out;

    char* ws = (char*)d_ws;
    float* xcur = (float*)ws;                       ws += (size_t)NROW * D_  * 4;  // fp32 residual stream
    __hip_bfloat16* lnb = (__hip_bfloat16*)ws;      ws += (size_t)NROW * D_  * 2;  // LN output (bf16 A-operand)
    float* xg5  = (float*)ws;                       ws += (size_t)S_ * 4096  * 4;  // gate proj fp32 [s][2][4][64][8]
    __hip_bfloat16* hb  = (__hip_bfloat16*)ws;      ws += (size_t)NROW * H_  * 2;  // LSTM h (bf16 A-operand)
    __hip_bfloat16* f1  = (__hip_bfloat16*)ws;      ws += (size_t)NROW * DI_ * 2;  // FFN hidden (bf16 A-operand)
    __hip_bfloat16* wihb = (__hip_bfloat16*)ws;     ws += (size_t)L_ * G4H * D_ * 2;
    __hip_bfloat16* wfcb = (__hip_bfloat16*)ws;     ws += (size_t)L_ * D_ * H_ * 2;
    __hip_bfloat16* w1b  = (__hip_bfloat16*)ws;     ws += (size_t)L_ * DI_ * D_ * 2;
    __hip_bfloat16* w2b  = (__hip_bfloat16*)ws;     ws += (size_t)L_ * D_ * DI_ * 2;

    // one-time (per launch) weight conversions to bf16
    {
        int n4;
        n4 = L_ * G4H * D_ / 4;
        w2bf_kernel<<<(n4 + 255) / 256, 256, 0, stream>>>(wih, wihb, n4);
        n4 = L_ * D_ * H_ / 4;
        w2bf_kernel<<<(n4 + 255) / 256, 256, 0, stream>>>(wfc, wfcb, n4);
        n4 = L_ * DI_ * D_ / 4;
        w2bf_kernel<<<(n4 + 255) / 256, 256, 0, stream>>>(w1, w1b, n4);
        n4 = L_ * D_ * DI_ / 4;
        w2bf_kernel<<<(n4 + 255) / 256, 256, 0, stream>>>(w2, w2b, n4);
    }

    hipMemcpyAsync(xcur, src, (size_t)NROW * D_ * sizeof(float),
                   hipMemcpyDeviceToDevice, stream);

    for (int l = 0; l < L_; l++) {
        // --- janossy layer ---
        ln_kernel<<<NROW, 256, 0, stream>>>(xcur, ln1_g + (size_t)l * D_,
                                            ln1_b + (size_t)l * D_, lnb);
        mfma_gemm<0, 0, 0, 2><<<dim3(G4H / 64, NROW / 64), 256, 0, stream>>>(
            lnb, wihb + (size_t)l * G4H * D_, nullptr, nullptr, xg5, NROW, G4H, D_);
        lstm_v7_kernel<<<dim3(S_, 2), 256, 0, stream>>>(
            xg5, whh + (size_t)l * G4H * H_, hb);
        mfma_gemm<0, 0, 1, 0><<<dim3(D_ / 64, NROW / 64), 256, 0, stream>>>(
            hb, wfcb + (size_t)l * D_ * H_, nullptr, xcur, xcur, NROW, D_, H_);
        // --- FFN ---
        ln_kernel<<<NROW, 256, 0, stream>>>(xcur, ln2_g + (size_t)l * D_,
                                            ln2_b + (size_t)l * D_, lnb);
        mfma_gemm<1, 1, 0, 1><<<dim3(DI_ / 64, NROW / 64), 256, 0, stream>>>(
            lnb, w1b + (size_t)l * DI_ * D_, b1 + (size_t)l * DI_, nullptr, f1, NROW, DI_, D_);
        mfma_gemm<1, 0, 1, 0><<<dim3(D_ / 64, NROW / 64), 256, 0, stream>>>(
            f1, w2b + (size_t)l * D_ * DI_, b2 + (size_t)l * D_, xcur, xcur, NROW, D_, DI_);
    }
    final_kernel<<<NROW, 256, 0, stream>>>(xcur, lnf_g, lnf_b, wprj, out);
}

// Round 4
// 713.455 us; speedup vs baseline: 1.3327x; 1.1587x over previous
//
#include <hip/hip_runtime.h>
#include <hip/hip_bf16.h>

#define B_ 16
#define S_ 80
#define D_ 512
#define H_ 64
#define DI_ 2048
#define L_ 6
#define G4H 256            // 4*H
#define NROW (B_ * S_)     // 1280 rows = (b, s)
#define EPS_ 1e-6f

typedef __attribute__((ext_vector_type(8))) short short8;
typedef __attribute__((ext_vector_type(4))) float f32x4;

// ---------------- math helpers ----------------
__device__ __forceinline__ float sigmoidf_(float x) {
    return __fdividef(1.0f, 1.0f + __expf(-x));
}
__device__ __forceinline__ float tanh_(float x) {
    return __fdividef(2.0f, 1.0f + __expf(-2.0f * x)) - 1.0f;
}
__device__ __forceinline__ short f2bf(float f) {
    __hip_bfloat16 h = __float2bfloat16(f);   // RNE
    return *reinterpret_cast<short*>(&h);
}

// Barrier that waits only on LDS traffic (lgkmcnt), NOT on in-flight global loads.
__device__ __forceinline__ void lds_barrier() {
    __asm__ volatile("s_waitcnt lgkmcnt(0)\n\ts_barrier" ::: "memory");
}

// ---------------- fp32 -> bf16 weight conversion (once per launch) ----------------
__global__ __launch_bounds__(256)
void w2bf_kernel(const float* __restrict__ s, __hip_bfloat16* __restrict__ d, int n4) {
    int i = blockIdx.x * 256 + threadIdx.x;
    if (i < n4) {
        float4 v = reinterpret_cast<const float4*>(s)[i];
        short4 o;
        o.x = f2bf(v.x); o.y = f2bf(v.y); o.z = f2bf(v.z); o.w = f2bf(v.w);
        reinterpret_cast<short4*>(d)[i] = o;
    }
}

// ---------------- LayerNorm: one block per row, shuffle reduce (2 barriers) ----------------
__global__ __launch_bounds__(256)
void ln_kernel(const float* __restrict__ x, const float* __restrict__ g,
               const float* __restrict__ b, __hip_bfloat16* __restrict__ out) {
    int row = blockIdx.x;
    int t = threadIdx.x;
    const float* xr = x + (size_t)row * D_;
    float v0 = xr[t], v1 = xr[t + 256];
    __shared__ float ws4[4], qs4[4];
    float s = v0 + v1;
    #pragma unroll
    for (int o = 32; o > 0; o >>= 1) s += __shfl_down(s, o);
    if ((t & 63) == 0) ws4[t >> 6] = s;
    __syncthreads();
    float m = (ws4[0] + ws4[1] + ws4[2] + ws4[3]) * (1.0f / (float)D_);
    float d0 = v0 - m, d1 = v1 - m;
    float q = d0 * d0 + d1 * d1;
    #pragma unroll
    for (int o = 32; o > 0; o >>= 1) q += __shfl_down(q, o);
    if ((t & 63) == 0) qs4[t >> 6] = q;
    __syncthreads();
    float rs = rsqrtf((qs4[0] + qs4[1] + qs4[2] + qs4[3]) * (1.0f / (float)D_) + EPS_);
    __hip_bfloat16* orow = out + (size_t)row * D_;
    orow[t]       = __float2bfloat16(d0 * rs * g[t]       + b[t]);
    orow[t + 256] = __float2bfloat16(d1 * rs * g[t + 256] + b[t + 256]);
}

// ---------------- bf16 MFMA GEMM: C[M,N] = A[M,K] @ W[N,K]^T (+bias)(+relu)(+res) -----------
// OUT_MODE: 0 = fp32 row-major, 1 = bf16 row-major,
//           2 = fp32 xg5 layout [s][half][gate][unit64][slot8]  (half=b>>3, slot=b&7)
template<int WITH_BIAS, int WITH_RELU, int WITH_RES, int OUT_MODE>
__global__ __launch_bounds__(256)
void mfma_gemm(const __hip_bfloat16* __restrict__ A, const __hip_bfloat16* __restrict__ W,
               const float* __restrict__ bias, const float* __restrict__ res,
               void* __restrict__ C, int M, int N, int K) {
    const int LDT = 72;  // LDS row stride in shorts (144B rows, 16B-aligned)
    __shared__ short As[64 * LDT];
    __shared__ short Ws[64 * LDT];

    int tid  = threadIdx.x;
    int wave = tid >> 6, lane = tid & 63;
    int quad = lane >> 4, l16 = lane & 15;
    int m_off = (wave >> 1) * 32, n_off = (wave & 1) * 32;
    int m0 = blockIdx.y * 64, n0 = blockIdx.x * 64;

    int r = tid >> 2, c = tid & 3;           // staging: row 0..63, 16-elem chunk 0..3
    const short* Ag = reinterpret_cast<const short*>(A);
    const short* Wg = reinterpret_cast<const short*>(W);

    f32x4 acc00 = {0.f,0.f,0.f,0.f}, acc01 = acc00, acc10 = acc00, acc11 = acc00;

    short8 avA[2], avW[2];                   // staged tile in registers
    auto load_tile = [&](int k0) {
        const short* arow = &Ag[(size_t)(m0 + r) * K + k0 + c * 16];
        avA[0] = *reinterpret_cast<const short8*>(arow);
        avA[1] = *reinterpret_cast<const short8*>(arow + 8);
        const short* wrow = &Wg[(size_t)(n0 + r) * K + k0 + c * 16];
        avW[0] = *reinterpret_cast<const short8*>(wrow);
        avW[1] = *reinterpret_cast<const short8*>(wrow + 8);
    };

    load_tile(0);                            // prologue
    for (int k0 = 0; k0 < K; k0 += 64) {
        lds_barrier();                       // prev frag reads done; vmem stays in flight
        *reinterpret_cast<short8*>(&As[r * LDT + c * 16])     = avA[0];
        *reinterpret_cast<short8*>(&As[r * LDT + c * 16 + 8]) = avA[1];
        *reinterpret_cast<short8*>(&Ws[r * LDT + c * 16])     = avW[0];
        *reinterpret_cast<short8*>(&Ws[r * LDT + c * 16 + 8]) = avW[1];
        lds_barrier();
        if (k0 + 64 < K) load_tile(k0 + 64); // issue next loads; consumed next iteration

        #pragma unroll
        for (int kc = 0; kc < 2; kc++) {
            short8 a0 = *reinterpret_cast<const short8*>(&As[(m_off + l16) * LDT + kc * 32 + quad * 8]);
            short8 a1 = *reinterpret_cast<const short8*>(&As[(m_off + 16 + l16) * LDT + kc * 32 + quad * 8]);
            short8 b0 = *reinterpret_cast<const short8*>(&Ws[(n_off + l16) * LDT + kc * 32 + quad * 8]);
            short8 b1 = *reinterpret_cast<const short8*>(&Ws[(n_off + 16 + l16) * LDT + kc * 32 + quad * 8]);
            acc00 = __builtin_amdgcn_mfma_f32_16x16x32_bf16(a0, b0, acc00, 0, 0, 0);
            acc01 = __builtin_amdgcn_mfma_f32_16x16x32_bf16(a0, b1, acc01, 0, 0, 0);
            acc10 = __builtin_amdgcn_mfma_f32_16x16x32_bf16(a1, b0, acc10, 0, 0, 0);
            acc11 = __builtin_amdgcn_mfma_f32_16x16x32_bf16(a1, b1, acc11, 0, 0, 0);
        }
    }

    f32x4 accs[2][2] = {{acc00, acc01}, {acc10, acc11}};
    #pragma unroll
    for (int fi = 0; fi < 2; fi++) {
        #pragma unroll
        for (int fj = 0; fj < 2; fj++) {
            int coln = n0 + n_off + fj * 16 + l16;
            float bv = WITH_BIAS ? bias[coln] : 0.0f;
            #pragma unroll
            for (int rr = 0; rr < 4; rr++) {
                int rowm = m0 + m_off + fi * 16 + quad * 4 + rr;
                float v = accs[fi][fj][rr];
                if (WITH_BIAS) v += bv;
                if (WITH_RELU) v = fmaxf(v, 0.0f);
                if (WITH_RES)  v += res[(size_t)rowm * N + coln];
                if (OUT_MODE == 0) {
                    reinterpret_cast<float*>(C)[(size_t)rowm * N + coln] = v;
                } else if (OUT_MODE == 1) {
                    reinterpret_cast<__hip_bfloat16*>(C)[(size_t)rowm * N + coln] = __float2bfloat16(v);
                } else {
                    int b_ = rowm / S_;
                    int s_ = rowm - b_ * S_;
                    int gate = coln >> 6, u = coln & 63;
                    int half = b_ >> 3, slot = b_ & 7;
                    reinterpret_cast<float*>(C)[
                        ((((size_t)(s_ * 2 + half) * 4 + gate) * 64 + u) << 3) + slot] = v;
                }
            }
        }
    }
}

// ---------------- MFMA LSTM v8: v4 structure, 8 waves, 1 state/lane ----------------
// v4's step chain (1650cy) is dominated by per-wave VALU transcendental issue/latency
// (~10 transc/state x 2 states/lane at 1/4-rate) + exposed ds/MFMA/xv stalls at
// 1 wave/SIMD. v8 keeps v4's layout EXACTLY but launches 512 threads: 8 waves =
// (unit-group wv 0..3) x (state-half rp 0..1). Both rp-partners compute the same
// 8 MFMAs (MFMA pipe 93% idle - duplication free), each runs the nonlinearity for
// ONE state/lane (half the transc chain), and the partner wave's issue fills the
// other's stalls (2 waves/SIMD). Grid (80,2): (position i, batch half).
__global__ __launch_bounds__(512, 1)
void lstm_v8_kernel(const float* __restrict__ xg5,  // [S][2][4][64][8] fp32
                    const float* __restrict__ whh,  // [4H, H] fp32 (layer slice)
                    __hip_bfloat16* __restrict__ hlast) {  // [B, S, H]
    const int i    = blockIdx.x;      // output position 0..79
    const int bh   = blockIdx.y;      // batch half 0..1
    const int tid  = threadIdx.x;
    const int wave = tid >> 6, lane = tid & 63;
    const int wv   = wave & 3;        // unit group 0..3
    const int rp   = wave >> 2;       // state-half 0..1 (which acc row this wave owns)
    const int quad = lane >> 4, l16 = lane & 15;
    const int unit = wv * 16 + l16;   // hidden unit owned on the C side

    // Whh B-fragments (bf16), one-time. Tile g: col n = l16 <-> whh row g*64 + unit.
    short8 bfrag[4][2];
    #pragma unroll
    for (int g = 0; g < 4; g++) {
        const float* wr = &whh[(size_t)(g * 64 + unit) * H_];
        #pragma unroll
        for (int kc = 0; kc < 2; kc++) {
            float4 x0 = *(const float4*)(wr + kc * 32 + quad * 8);
            float4 x1 = *(const float4*)(wr + kc * 32 + quad * 8 + 4);
            short8 v;
            v[0] = f2bf(x0.x); v[1] = f2bf(x0.y); v[2] = f2bf(x0.z); v[3] = f2bf(x0.w);
            v[4] = f2bf(x1.x); v[5] = f2bf(x1.y); v[6] = f2bf(x1.z); v[7] = f2bf(x1.w);
            bfrag[g][kc] = v;
        }
    }

    // h in LDS, double-buffered by step parity; 72-short rows (144B, 16B-aligned)
    __shared__ __attribute__((aligned(16))) short hsh[2][16][72];
    for (int idx = tid; idx < 2 * 16 * 72; idx += 512)
        reinterpret_cast<short*>(hsh)[idx] = 0;

    float cst = 0.f;   // this wave's single cell state per lane
    float hvv = 0.f;

    // xg float2 addresses: (((s*2+bh)*4 + g)*64 + unit)*8 + quad*2  (identical to v4)
    size_t xoff[4];
    #pragma unroll
    for (int g = 0; g < 4; g++)
        xoff[g] = ((((size_t)bh * 4 + g) * 64 + unit) << 3) + quad * 2;

    float2 xv[4];
    {
        int s0 = (0 == i) ? (S_ - 1) : 0;
        #pragma unroll
        for (int g = 0; g < 4; g++)
            xv[g] = *reinterpret_cast<const float2*>(&xg5[(size_t)s0 * 4096 + xoff[g]]);
    }

    lds_barrier();  // LDS zero-init visible

    for (int t = 0; t < S_; t++) {
        const int pb = t & 1;
        short8 af0 = *reinterpret_cast<const short8*>(&hsh[pb][l16][quad * 8]);
        short8 af1 = *reinterpret_cast<const short8*>(&hsh[pb][l16][32 + quad * 8]);

        f32x4 acc[4];
        #pragma unroll
        for (int g = 0; g < 4; g++) {
            f32x4 a = {xv[g].x, xv[g].y, 0.f, 0.f};  // rows 2,3 unused
            acc[g] = a;
        }

        // prefetch next step's xg (xv just consumed; stays in flight across the barrier)
        if (t + 1 < S_) {
            int tn = t + 1;
            int sn = (tn == i) ? (S_ - 1) : ((tn == S_ - 1) ? i : tn);
            #pragma unroll
            for (int g = 0; g < 4; g++)
                xv[g] = *reinterpret_cast<const float2*>(&xg5[(size_t)sn * 4096 + xoff[g]]);
        }

        #pragma unroll
        for (int g = 0; g < 4; g++) {
            acc[g] = __builtin_amdgcn_mfma_f32_16x16x32_bf16(af0, bfrag[g][0], acc[g], 0, 0, 0);
            acc[g] = __builtin_amdgcn_mfma_f32_16x16x32_bf16(af1, bfrag[g][1], acc[g], 0, 0, 0);
        }

        // this wave's single state: acc row rp (wave-uniform select, no scratch)
        float gi = rp ? acc[0][1] : acc[0][0];
        float gf = rp ? acc[1][1] : acc[1][0];
        float gg = rp ? acc[2][1] : acc[2][0];
        float go = rp ? acc[3][1] : acc[3][0];

        float ig = sigmoidf_(gi);
        float fg = sigmoidf_(gf);
        float gv = tanh_(gg);
        float og = sigmoidf_(go);
        float cc = fg * cst + ig * gv;
        cst = cc;
        float h = og * tanh_(cc);
        hvv = h;
        hsh[pb ^ 1][quad * 4 + rp][unit] = f2bf(h);

        lds_barrier();
    }

    {
        int b = bh * 8 + quad * 2 + rp;
        hlast[((size_t)b * S_ + i) * H_ + unit] = __float2bfloat16(hvv);
    }
}

// ---------------- final LN + projection to one logit per row ----------------
__global__ __launch_bounds__(256)
void final_kernel(const float* __restrict__ x, const float* __restrict__ g,
                  const float* __restrict__ b, const float* __restrict__ wprj,
                  float* __restrict__ out) {
    int row = blockIdx.x;
    int t = threadIdx.x;
    const float* xr = x + (size_t)row * D_;
    float v0 = xr[t], v1 = xr[t + 256];
    __shared__ float red[256];
    red[t] = v0 + v1;
    __syncthreads();
    for (int o = 128; o > 0; o >>= 1) { if (t < o) red[t] += red[t + o]; __syncthreads(); }
    float m = red[0] * (1.0f / (float)D_);
    __syncthreads();
    float d0 = v0 - m, d1 = v1 - m;
    red[t] = d0 * d0 + d1 * d1;
    __syncthreads();
    for (int o = 128; o > 0; o >>= 1) { if (t < o) red[t] += red[t + o]; __syncthreads(); }
    float rs = rsqrtf(red[0] * (1.0f / (float)D_) + EPS_);
    __syncthreads();
    float y0 = (d0 * rs * g[t] + b[t]) * wprj[t];
    float y1 = (d1 * rs * g[t + 256] + b[t + 256]) * wprj[t + 256];
    red[t] = y0 + y1;
    __syncthreads();
    for (int o = 128; o > 0; o >>= 1) { if (t < o) red[t] += red[t + o]; __syncthreads(); }
    if (t == 0) out[row] = red[0];
}

// ---------------- host ----------------
extern "C" void kernel_launch(void* const* d_in, const int* in_sizes, int n_in,
                              void* d_out, int out_size, void* d_ws, size_t ws_size,
                              hipStream_t stream) {
    const float* src   = (const float*)d_in[0];
    const float* ln1_g = (const float*)d_in[2];
    const float* ln1_b = (const float*)d_in[3];
    const float* wih   = (const float*)d_in[4];   // [L, 4H, D]
    const float* whh   = (const float*)d_in[5];   // [L, 4H, H]
    const float* wfc   = (const float*)d_in[6];   // [L, D, H]
    const float* ln2_g = (const float*)d_in[7];
    const float* ln2_b = (const float*)d_in[8];
    const float* w1    = (const float*)d_in[9];   // [L, DI, D]
    const float* b1    = (const float*)d_in[10];  // [L, DI]
    const float* w2    = (const float*)d_in[11];  // [L, D, DI]
    const float* b2    = (const float*)d_in[12];  // [L, D]
    const float* lnf_g = (const float*)d_in[13];
    const float* lnf_b = (const float*)d_in[14];
    const float* wprj  = (const float*)d_in[15];  // [1, D]
    float* out = (float*)d_out;

    char* ws = (char*)d_ws;
    float* xcur = (float*)ws;                       ws += (size_t)NROW * D_  * 4;  // fp32 residual stream
    __hip_bfloat16* lnb = (__hip_bfloat16*)ws;      ws += (size_t)NROW * D_  * 2;  // LN output (bf16 A-operand)
    float* xg5  = (float*)ws;                       ws += (size_t)S_ * 4096  * 4;  // gate proj fp32 [s][2][4][64][8]
    __hip_bfloat16* hb  = (__hip_bfloat16*)ws;      ws += (size_t)NROW * H_  * 2;  // LSTM h (bf16 A-operand)
    __hip_bfloat16* f1  = (__hip_bfloat16*)ws;      ws += (size_t)NROW * DI_ * 2;  // FFN hidden (bf16 A-operand)
    __hip_bfloat16* wihb = (__hip_bfloat16*)ws;     ws += (size_t)L_ * G4H * D_ * 2;
    __hip_bfloat16* wfcb = (__hip_bfloat16*)ws;     ws += (size_t)L_ * D_ * H_ * 2;
    __hip_bfloat16* w1b  = (__hip_bfloat16*)ws;     ws += (size_t)L_ * DI_ * D_ * 2;
    __hip_bfloat16* w2b  = (__hip_bfloat16*)ws;     ws += (size_t)L_ * D_ * DI_ * 2;

    // one-time (per launch) weight conversions to bf16
    {
        int n4;
        n4 = L_ * G4H * D_ / 4;
        w2bf_kernel<<<(n4 + 255) / 256, 256, 0, stream>>>(wih, wihb, n4);
        n4 = L_ * D_ * H_ / 4;
        w2bf_kernel<<<(n4 + 255) / 256, 256, 0, stream>>>(wfc, wfcb, n4);
        n4 = L_ * DI_ * D_ / 4;
        w2bf_kernel<<<(n4 + 255) / 256, 256, 0, stream>>>(w1, w1b, n4);
        n4 = L_ * D_ * DI_ / 4;
        w2bf_kernel<<<(n4 + 255) / 256, 256, 0, stream>>>(w2, w2b, n4);
    }

    hipMemcpyAsync(xcur, src, (size_t)NROW * D_ * sizeof(float),
                   hipMemcpyDeviceToDevice, stream);

    for (int l = 0; l < L_; l++) {
        // --- janossy layer ---
        ln_kernel<<<NROW, 256, 0, stream>>>(xcur, ln1_g + (size_t)l * D_,
                                            ln1_b + (size_t)l * D_, lnb);
        mfma_gemm<0, 0, 0, 2><<<dim3(G4H / 64, NROW / 64), 256, 0, stream>>>(
            lnb, wihb + (size_t)l * G4H * D_, nullptr, nullptr, xg5, NROW, G4H, D_);
        lstm_v8_kernel<<<dim3(S_, 2), 512, 0, stream>>>(
            xg5, whh + (size_t)l * G4H * H_, hb);
        mfma_gemm<0, 0, 1, 0><<<dim3(D_ / 64, NROW / 64), 256, 0, stream>>>(
            hb, wfcb + (size_t)l * D_ * H_, nullptr, xcur, xcur, NROW, D_, H_);
        // --- FFN ---
        ln_kernel<<<NROW, 256, 0, stream>>>(xcur, ln2_g + (size_t)l * D_,
                                            ln2_b + (size_t)l * D_, lnb);
        mfma_gemm<1, 1, 0, 1><<<dim3(DI_ / 64, NROW / 64), 256, 0, stream>>>(
            lnb, w1b + (size_t)l * DI_ * D_, b1 + (size_t)l * DI_, nullptr, f1, NROW, DI_, D_);
        mfma_gemm<1, 0, 1, 0><<<dim3(D_ / 64, NROW / 64), 256, 0, stream>>>(
            f1, w2b + (size_t)l * D_ * DI_, b2 + (size_t)l * D_, xcur, xcur, NROW, D_, DI_);
    }
    final_kernel<<<NROW, 256, 0, stream>>>(xcur, lnf_g, lnf_b, wprj, out);
}